// Round 5
// baseline (435.981 us; speedup 1.0000x reference)
//
#include <hip/hip_runtime.h>
#include <hip/hip_cooperative_groups.h>
#include <math.h>

namespace cg = cooperative_groups;

#define B 2048
#define D 512
#define NC 32
#define SLICES 32
#define TOP2_BLOCKS (NC * SLICES)        // 1024
#define GRID_BLOCKS (NC + TOP2_BLOCKS)   // 1056
#define CMIN_BLOCKS 256                  // 1024 pair slots / 4 waves

// ---------------------------------------------------------------------------
// Workspace: float centers[NC][D]; float blk_top[NC][SLICES][2];
//            float cmin[CMIN_BLOCKS];  float li[NC]
// ---------------------------------------------------------------------------

// Build class-c member list in LDS via wave shuffle-scan (deterministic).
__device__ inline int build_slist(const int* __restrict__ target, int c,
                                  int* slist, int* wtot) {
    const int t = threadIdx.x;
    const int wave = t >> 6;
    const int lane = t & 63;
    const int base = t * 8;
    int flags[8];
    int local = 0;
#pragma unroll
    for (int k = 0; k < 8; ++k) {
        flags[k] = (target[base + k] == c) ? 1 : 0;
        local += flags[k];
    }
    int incl = local;
#pragma unroll
    for (int off = 1; off < 64; off <<= 1) {
        const int v = __shfl_up(incl, off, 64);
        if (lane >= off) incl += v;
    }
    if (lane == 63) wtot[wave] = incl;
    __syncthreads();
    int wbase = 0;
    for (int w = 0; w < wave; ++w) wbase += wtot[w];
    const int n = wtot[0] + wtot[1] + wtot[2] + wtot[3];
    int pos = wbase + incl - local;
#pragma unroll
    for (int k = 0; k < 8; ++k) {
        if (flags[k]) slist[pos++] = base + k;
    }
    __syncthreads();
    return n;
}

// 64 lanes split D (8 floats = 32B each); butterfly-reduced ssd on all lanes.
__device__ inline float wave_ssd(const float* __restrict__ ra,
                                 const float* __restrict__ rb, int lane) {
    const float4* a = (const float4*)ra + lane * 2;
    const float4* b = (const float4*)rb + lane * 2;
    const float4 u0 = a[0], u1 = a[1];
    const float4 v0 = b[0], v1 = b[1];
    float d, ssd = 0.f;
    d = u0.x - v0.x; ssd += d * d;
    d = u0.y - v0.y; ssd += d * d;
    d = u0.z - v0.z; ssd += d * d;
    d = u0.w - v0.w; ssd += d * d;
    d = u1.x - v1.x; ssd += d * d;
    d = u1.y - v1.y; ssd += d * d;
    d = u1.z - v1.z; ssd += d * d;
    d = u1.w - v1.w; ssd += d * d;
#pragma unroll
    for (int off = 32; off > 0; off >>= 1) ssd += __shfl_xor(ssd, off, 64);
    return ssd;
}

// ---------------- phase bodies (shared by coop + fallback paths) ----------

__device__ void phase1_work(int bid, const float* __restrict__ y,
                            const int* __restrict__ target,
                            float* __restrict__ centers,
                            float* __restrict__ blk_top) {
    const int t = threadIdx.x;
    const int wave = t >> 6;
    const int lane = t & 63;
    __shared__ int slist[B];
    __shared__ int wtot[4];
    __shared__ float s0[4], s1[4];

    if (bid < NC) {
        // ---- centers: thread owns dims t and t+256 ----
        const int c = bid;
        const int n = build_slist(target, c, slist, wtot);
        float acc0 = 0.f, acc1 = 0.f;
        for (int m = 0; m < n; ++m) {
            const float* row = y + (size_t)slist[m] * D;
            acc0 += row[t];
            acc1 += row[t + 256];
        }
        const float den = fmaxf((float)n, 1.0f);
        centers[c * D + t]       = acc0 / den;
        centers[c * D + t + 256] = acc1 / den;
        return;
    }

    // ---- top2 slice: one wave per pair slot ----
    const int c = (bid - NC) >> 5;
    const int s = (bid - NC) & 31;
    const int n = build_slist(target, c, slist, wtot);

    float t0 = -INFINITY, t1 = -INFINITY;
    const int nn = n * n;
    int p = s * 4 + wave;                 // wave-uniform slot
    if (p < nn) {
        int i = p / n;                    // single division
        int j = p - i * n;
        while (p < nn) {
            if (i < j) {
                const float dd = sqrtf(wave_ssd(y + (size_t)slist[i] * D,
                                                y + (size_t)slist[j] * D, lane));
                if (dd > t0) { t1 = t0; t0 = dd; }
                else if (dd > t1) { t1 = dd; }
            }
            p += SLICES * 4;
            j += SLICES * 4;
            while (j >= n) { j -= n; ++i; }   // 1-3 scalar iters (stride 128, n~64)
        }
    }

    if (lane == 0) { s0[wave] = t0; s1[wave] = t1; }
    __syncthreads();
    if (t == 0) {
        float b0 = -INFINITY, b1 = -INFINITY;
        for (int w = 0; w < 4; ++w) {
            const float a0 = s0[w], a1 = s1[w];
            if (a0 > b0) { b1 = b0; b0 = a0; } else if (a0 > b1) { b1 = a0; }
            if (a1 > b0) { b1 = b0; b0 = a1; } else if (a1 > b1) { b1 = a1; }
        }
        blk_top[(c * SLICES + s) * 2]     = b0;
        blk_top[(c * SLICES + s) * 2 + 1] = b1;
    }
}

__device__ void phase2_work(int bid, const float* __restrict__ centers,
                            const float* __restrict__ blk_top,
                            float* __restrict__ cmin, float* __restrict__ li) {
    const int t = threadIdx.x;
    const int wave = t >> 6;
    const int lane = t & 63;

    if (bid < CMIN_BLOCKS) {
        // ---- center-min: one (i,j) slot per wave ----
        __shared__ float sm[4];
        const int slot = bid * 4 + wave;
        const int i = slot >> 5;
        const int j = slot & 31;
        float dd = INFINITY;
        if (i < j) dd = sqrtf(wave_ssd(centers + i * D, centers + j * D, lane));
        if (lane == 0) sm[wave] = dd;
        __syncthreads();
        if (t == 0) {
            float m = INFINITY;
            for (int w = 0; w < 4; ++w) m = fminf(m, sm[w]);
            cmin[bid] = m;
        }
        return;
    }
    if (bid < CMIN_BLOCKS + NC && wave == 0) {
        // ---- per-class top-2 merge: 64 slice-partials on 64 lanes ----
        const int c = bid - CMIN_BLOCKS;
        float t0 = blk_top[c * SLICES * 2 + lane];
        float t1 = -INFINITY;
#pragma unroll
        for (int off = 32; off > 0; off >>= 1) {
            const float o0 = __shfl_xor(t0, off, 64);
            const float o1 = __shfl_xor(t1, off, 64);
            if (o0 > t0) { t1 = fmaxf(t0, o1); t0 = o0; }
            else         { t1 = fmaxf(t1, o0); }
        }
        if (lane == 0) li[c] = 2.0f / (t0 + t1);
    }
}

__device__ void phase3_work(const float* __restrict__ cmin,
                            const float* __restrict__ li,
                            float* __restrict__ out) {
    const int t = threadIdx.x;
    const int wave = t >> 6;
    const int lane = t & 63;
    __shared__ float mn_sh[4];

    float v = cmin[wave * 64 + lane];
#pragma unroll
    for (int off = 32; off > 0; off >>= 1) v = fminf(v, __shfl_xor(v, off, 64));
    if (lane == 0) mn_sh[wave] = v;
    __syncthreads();
    if (t == 0) {
        float m = INFINITY;
        for (int w = 0; w < 4; ++w) m = fminf(m, mn_sh[w]);
        float s = 0.f;
        for (int c = 0; c < NC; ++c) s += li[c];
        out[0] = 1.0f * s + 0.5f * fmaxf(10.0f - m, 0.0f);
    }
}

// ---------------- cooperative single-launch kernel -------------------------

__global__ void __launch_bounds__(256, 8)
coop_kernel(const float* __restrict__ y, const int* __restrict__ target,
            float* __restrict__ centers, float* __restrict__ blk_top,
            float* __restrict__ cmin, float* __restrict__ li,
            float* __restrict__ out) {
    cg::grid_group grid = cg::this_grid();
    const int bid = blockIdx.x;

    phase1_work(bid, y, target, centers, blk_top);
    __threadfence();
    grid.sync();
    if (bid < CMIN_BLOCKS + NC) phase2_work(bid, centers, blk_top, cmin, li);
    __threadfence();
    grid.sync();
    if (bid == 0) phase3_work(cmin, li, out);
}

// ---------------- fallback (plain 3-launch) kernels ------------------------

__global__ void __launch_bounds__(256, 8)
p1_kernel(const float* __restrict__ y, const int* __restrict__ target,
          float* __restrict__ centers, float* __restrict__ blk_top) {
    phase1_work(blockIdx.x, y, target, centers, blk_top);
}
__global__ void __launch_bounds__(256, 8)
p2_kernel(const float* __restrict__ centers, const float* __restrict__ blk_top,
          float* __restrict__ cmin, float* __restrict__ li) {
    phase2_work(blockIdx.x, centers, blk_top, cmin, li);
}
__global__ void __launch_bounds__(256, 8)
p3_kernel(const float* __restrict__ cmin, const float* __restrict__ li,
          float* __restrict__ out) {
    phase3_work(cmin, li, out);
}

extern "C" void kernel_launch(void* const* d_in, const int* in_sizes, int n_in,
                              void* d_out, int out_size, void* d_ws, size_t ws_size,
                              hipStream_t stream) {
    const float* y      = (const float*)d_in[0];
    const int*   target = (const int*)d_in[1];
    float*       out    = (float*)d_out;

    float* centers = (float*)d_ws;
    float* blk_top = centers + NC * D;
    float* cmin    = blk_top + NC * SLICES * 2;
    float* li      = cmin + CMIN_BLOCKS;

    void* args[] = {(void*)&y, (void*)&target, (void*)&centers, (void*)&blk_top,
                    (void*)&cmin, (void*)&li, (void*)&out};
    hipError_t err = hipLaunchCooperativeKernel((const void*)coop_kernel,
                                                dim3(GRID_BLOCKS), dim3(256),
                                                args, 0, stream);
    if (err != hipSuccess) {
        // fallback: equivalent 3-launch pipeline
        p1_kernel<<<GRID_BLOCKS, 256, 0, stream>>>(y, target, centers, blk_top);
        p2_kernel<<<CMIN_BLOCKS + NC, 256, 0, stream>>>(centers, blk_top, cmin, li);
        p3_kernel<<<1, 256, 0, stream>>>(cmin, li, out);
    }
}

// Round 6
// 102.934 us; speedup vs baseline: 4.2355x; 4.2355x over previous
//
#include <hip/hip_runtime.h>
#include <math.h>

#define B 2048
#define D 512
#define NC 32
#define RB 8                    // top2 row-blocks per class (RB*4 = 32 waves/class)
#define K2_BLOCKS (256 + NC)    // 256 center-min blocks + 32 merge blocks

// ---------------------------------------------------------------------------
// Workspace: float centers[NC][D]; float blk_top[NC][RB][2];
//            float cmin[256]; float li[NC]; int cnt
// ---------------------------------------------------------------------------

// Build class-c member list in LDS via wave shuffle-scan (deterministic,
// ascending index order). Thread t scans chunk [8t, 8t+8).
__device__ inline int build_slist(const int* __restrict__ target, int c,
                                  int* slist, int* wtot) {
    const int t = threadIdx.x;
    const int wave = t >> 6;
    const int lane = t & 63;
    const int base = t * 8;
    int flags[8];
    int local = 0;
#pragma unroll
    for (int k = 0; k < 8; ++k) {
        flags[k] = (target[base + k] == c) ? 1 : 0;
        local += flags[k];
    }
    int incl = local;
#pragma unroll
    for (int off = 1; off < 64; off <<= 1) {
        const int v = __shfl_up(incl, off, 64);
        if (lane >= off) incl += v;
    }
    if (lane == 63) wtot[wave] = incl;
    __syncthreads();
    int wbase = 0;
    for (int w = 0; w < wave; ++w) wbase += wtot[w];
    const int n = wtot[0] + wtot[1] + wtot[2] + wtot[3];
    int pos = wbase + incl - local;
#pragma unroll
    for (int k = 0; k < 8; ++k) {
        if (flags[k]) slist[pos++] = base + k;
    }
    __syncthreads();
    return n;
}

// ---------------- K1: centers + top2 (row-cached) --------------------------

__global__ void k1_kernel(const float* __restrict__ y,
                          const int* __restrict__ target,
                          float* __restrict__ centers,
                          float* __restrict__ blk_top,
                          int* __restrict__ cnt) {
    const int c = blockIdx.x;
    const int t = threadIdx.x;
    const int wave = t >> 6;
    const int lane = t & 63;

    if (blockIdx.y == 0 && c == 0 && t == 0) *cnt = 0;  // reset K2 finish ctr

    __shared__ int slist[B];
    __shared__ int wtot[4];
    const int n = build_slist(target, c, slist, wtot);

    if (blockIdx.y == 0) {
        // -------- centers: thread owns dims t, t+256; 8-way unrolled gather
        float acc0 = 0.f, acc1 = 0.f;
        int m = 0;
        for (; m + 8 <= n; m += 8) {
#pragma unroll
            for (int k = 0; k < 8; ++k) {
                const float* r = y + (size_t)slist[m + k] * D;
                acc0 += r[t];
                acc1 += r[t + 256];
            }
        }
        for (; m < n; ++m) {
            const float* r = y + (size_t)slist[m] * D;
            acc0 += r[t];
            acc1 += r[t + 256];
        }
        const float den = fmaxf((float)n, 1.0f);
        centers[c * D + t]       = acc0 / den;
        centers[c * D + t + 256] = acc1 / den;
        return;
    }

    // -------- top2: wave caches row i in regs, streams rows j>i ------------
    const int wglob = (blockIdx.y - 1) * 4 + wave;   // 0..RB*4-1 (32)
    float t0 = -INFINITY, t1 = -INFINITY;
    const int nr = n - 1;                            // rows that have pairs
    for (int r = wglob; r < (nr + 1) / 2; r += RB * 4) {
#pragma unroll
        for (int h = 0; h < 2; ++h) {
            const int i = h ? (nr - 1 - r) : r;      // balanced: r <-> nr-1-r
            if (h && i == r) break;                  // odd middle row once
            const float4* ri = (const float4*)(y + (size_t)slist[i] * D) + lane * 2;
            const float4 a0 = ri[0], a1 = ri[1];     // row i cached in 8 VGPRs
            for (int j = i + 1; j < n; ++j) {
                const float4* rj = (const float4*)(y + (size_t)slist[j] * D) + lane * 2;
                const float4 b0 = rj[0], b1 = rj[1];
                float d, ssd = 0.f;
                d = a0.x - b0.x; ssd += d * d;
                d = a0.y - b0.y; ssd += d * d;
                d = a0.z - b0.z; ssd += d * d;
                d = a0.w - b0.w; ssd += d * d;
                d = a1.x - b1.x; ssd += d * d;
                d = a1.y - b1.y; ssd += d * d;
                d = a1.z - b1.z; ssd += d * d;
                d = a1.w - b1.w; ssd += d * d;
#pragma unroll
                for (int off = 32; off > 0; off >>= 1)
                    ssd += __shfl_xor(ssd, off, 64);
                const float dd = sqrtf(ssd);
                if (dd > t0) { t1 = t0; t0 = dd; }
                else if (dd > t1) { t1 = dd; }
            }
        }
    }

    __shared__ float s0[4], s1[4];
    if (lane == 0) { s0[wave] = t0; s1[wave] = t1; }
    __syncthreads();
    if (t == 0) {
        float b0 = -INFINITY, b1 = -INFINITY;
        for (int w = 0; w < 4; ++w) {
            const float a0 = s0[w], a1 = s1[w];
            if (a0 > b0) { b1 = b0; b0 = a0; } else if (a0 > b1) { b1 = a0; }
            if (a1 > b0) { b1 = b0; b0 = a1; } else if (a1 > b1) { b1 = a1; }
        }
        const int rb = blockIdx.y - 1;
        blk_top[(c * RB + rb) * 2]     = b0;
        blk_top[(c * RB + rb) * 2 + 1] = b1;
    }
}

// ---------------- K2: center-min + class merge + last-block finish ---------

__global__ void k2_kernel(const float* __restrict__ centers,
                          const float* __restrict__ blk_top,
                          float* __restrict__ cmin,
                          float* __restrict__ li,
                          int* __restrict__ cnt,
                          float* __restrict__ out) {
    const int bid = blockIdx.x;
    const int t = threadIdx.x;
    const int wave = t >> 6;
    const int lane = t & 63;

    if (bid < 256) {
        // ---- center-min: one (i,j) slot per wave, lanes split D ----
        __shared__ float sm[4];
        const int slot = bid * 4 + wave;
        const int i = slot >> 5;
        const int j = slot & 31;
        float dd = INFINITY;
        if (i < j) {
            const float4* ca = (const float4*)(centers + i * D) + lane * 2;
            const float4* cb = (const float4*)(centers + j * D) + lane * 2;
            const float4 u0 = ca[0], u1 = ca[1];
            const float4 v0 = cb[0], v1 = cb[1];
            float d, ssd = 0.f;
            d = u0.x - v0.x; ssd += d * d;
            d = u0.y - v0.y; ssd += d * d;
            d = u0.z - v0.z; ssd += d * d;
            d = u0.w - v0.w; ssd += d * d;
            d = u1.x - v1.x; ssd += d * d;
            d = u1.y - v1.y; ssd += d * d;
            d = u1.z - v1.z; ssd += d * d;
            d = u1.w - v1.w; ssd += d * d;
#pragma unroll
            for (int off = 32; off > 0; off >>= 1)
                ssd += __shfl_xor(ssd, off, 64);
            dd = sqrtf(ssd);
        }
        if (lane == 0) sm[wave] = dd;
        __syncthreads();
        if (t == 0) {
            float m = INFINITY;
            for (int w = 0; w < 4; ++w) m = fminf(m, sm[w]);
            cmin[bid] = m;
        }
    } else if (wave == 0) {
        // ---- per-class top-2 merge: RB*2 = 16 partials on 16 lanes ----
        const int c = bid - 256;
        float t0 = (lane < RB * 2) ? blk_top[c * RB * 2 + lane] : -INFINITY;
        float t1 = -INFINITY;
#pragma unroll
        for (int off = 32; off > 0; off >>= 1) {
            const float o0 = __shfl_xor(t0, off, 64);
            const float o1 = __shfl_xor(t1, off, 64);
            if (o0 > t0) { t1 = fmaxf(t0, o1); t0 = o0; }
            else         { t1 = fmaxf(t1, o0); }
        }
        if (lane == 0) li[c] = 2.0f / (t0 + t1);
    }

    // ---- last-arriving block does the tiny final combine ----
    __shared__ int isLast;
    __threadfence();
    __syncthreads();
    if (t == 0) {
        const int old = atomicAdd(cnt, 1);
        isLast = (old == K2_BLOCKS - 1) ? 1 : 0;
    }
    __syncthreads();
    if (isLast) {
        __threadfence();
        __shared__ float mn_sh[4];
        float v = cmin[wave * 64 + lane];
#pragma unroll
        for (int off = 32; off > 0; off >>= 1)
            v = fminf(v, __shfl_xor(v, off, 64));
        if (lane == 0) mn_sh[wave] = v;
        __syncthreads();
        if (t == 0) {
            float m = INFINITY;
            for (int w = 0; w < 4; ++w) m = fminf(m, mn_sh[w]);
            float s = 0.f;
            for (int c = 0; c < NC; ++c) s += li[c];
            out[0] = 1.0f * s + 0.5f * fmaxf(10.0f - m, 0.0f);
        }
    }
}

extern "C" void kernel_launch(void* const* d_in, const int* in_sizes, int n_in,
                              void* d_out, int out_size, void* d_ws, size_t ws_size,
                              hipStream_t stream) {
    const float* y      = (const float*)d_in[0];
    const int*   target = (const int*)d_in[1];
    float*       out    = (float*)d_out;

    float* centers = (float*)d_ws;
    float* blk_top = centers + NC * D;
    float* cmin    = blk_top + NC * RB * 2;
    float* li      = cmin + 256;
    int*   cnt     = (int*)(li + NC);

    k1_kernel<<<dim3(NC, RB + 1), 256, 0, stream>>>(y, target, centers, blk_top, cnt);
    k2_kernel<<<K2_BLOCKS, 256, 0, stream>>>(centers, blk_top, cmin, li, cnt, out);
}

// Round 7
// 78.496 us; speedup vs baseline: 5.5542x; 1.3113x over previous
//
#include <hip/hip_runtime.h>
#include <math.h>

#define B 2048
#define D 512
#define NC 32
#define S2 9                    // top2 slices per class (9 blocks x 4 waves = 36 subtile-waves)
#define K2_BLOCKS (256 + NC)    // 256 center-min blocks + 32 merge blocks

// ---------------------------------------------------------------------------
// Workspace: float centers[NC][D]; float blk_top[NC][S2][2];
//            float cmin[256]; float li[NC]; int cnt
// ---------------------------------------------------------------------------

// Build class-c member list in LDS via wave shuffle-scan (deterministic,
// ascending index order). Thread t scans chunk [8t, 8t+8).
__device__ inline int build_slist(const int* __restrict__ target, int c,
                                  int* slist, int* wtot) {
    const int t = threadIdx.x;
    const int wave = t >> 6;
    const int lane = t & 63;
    const int base = t * 8;
    int flags[8];
    int local = 0;
#pragma unroll
    for (int k = 0; k < 8; ++k) {
        flags[k] = (target[base + k] == c) ? 1 : 0;
        local += flags[k];
    }
    int incl = local;
#pragma unroll
    for (int off = 1; off < 64; off <<= 1) {
        const int v = __shfl_up(incl, off, 64);
        if (lane >= off) incl += v;
    }
    if (lane == 63) wtot[wave] = incl;
    __syncthreads();
    int wbase = 0;
    for (int w = 0; w < wave; ++w) wbase += wtot[w];
    const int n = wtot[0] + wtot[1] + wtot[2] + wtot[3];
    int pos = wbase + incl - local;
#pragma unroll
    for (int k = 0; k < 8; ++k) {
        if (flags[k]) slist[pos++] = base + k;
    }
    __syncthreads();
    return n;
}

// ---------------- K1: centers + top2 (lane-per-pair, 8x8 wave subtiles) ----

__global__ void __launch_bounds__(256)
k1_kernel(const float* __restrict__ y,
          const int* __restrict__ target,
          float* __restrict__ centers,
          float* __restrict__ blk_top,
          int* __restrict__ cnt) {
    const int c = blockIdx.x;
    const int t = threadIdx.x;
    const int wave = t >> 6;
    const int lane = t & 63;

    if (blockIdx.y == 0 && c == 0 && t == 0) *cnt = 0;  // reset K2 finish ctr

    __shared__ int slist[B];
    __shared__ int wtot[4];
    const int n = build_slist(target, c, slist, wtot);

    if (blockIdx.y == 0) {
        // -------- centers: thread owns dims t, t+256; 8-way unrolled gather
        float acc0 = 0.f, acc1 = 0.f;
        int m = 0;
        for (; m + 8 <= n; m += 8) {
#pragma unroll
            for (int k = 0; k < 8; ++k) {
                const float* r = y + (size_t)slist[m + k] * D;
                acc0 += r[t];
                acc1 += r[t + 256];
            }
        }
        for (; m < n; ++m) {
            const float* r = y + (size_t)slist[m] * D;
            acc0 += r[t];
            acc1 += r[t + 256];
        }
        const float den = fmaxf((float)n, 1.0f);
        centers[c * D + t]       = acc0 / den;
        centers[c * D + t + 256] = acc1 / den;
        return;
    }

    // -------- top2: one PAIR per LANE; wave = 8x8 subtile of the triangle --
    const int wg = (blockIdx.y - 1) * 4 + wave;  // 0..35
    const int nt = (n + 7) >> 3;                 // 8-row tiles
    const int nst = nt * (nt + 1) / 2;           // subtiles with ta <= tb
    const int di = lane >> 3;
    const int dj = lane & 7;

    float t0 = -INFINITY, t1 = -INFINITY;
    for (int st = wg; st < nst; st += S2 * 4) {
        // decode st -> (ta, tb), ta <= tb (row-major over upper triangle)
        int rem = st, ta = 0;
        while (rem >= nt - ta) { rem -= nt - ta; ++ta; }
        const int tb = ta + rem;
        const int i = ta * 8 + di;
        const int j = tb * 8 + dj;
        if (i < j && j < n) {
            const float4* pa = (const float4*)(y + (size_t)slist[i] * D);
            const float4* pb = (const float4*)(y + (size_t)slist[j] * D);
            float s0 = 0.f, s1 = 0.f, s2 = 0.f, s3 = 0.f;
            for (int k = 0; k < D / 4; k += 4) {
                float4 a, b; float d;
                a = pa[k];     b = pb[k];
                d = a.x - b.x; s0 += d * d;  d = a.y - b.y; s0 += d * d;
                d = a.z - b.z; s0 += d * d;  d = a.w - b.w; s0 += d * d;
                a = pa[k + 1]; b = pb[k + 1];
                d = a.x - b.x; s1 += d * d;  d = a.y - b.y; s1 += d * d;
                d = a.z - b.z; s1 += d * d;  d = a.w - b.w; s1 += d * d;
                a = pa[k + 2]; b = pb[k + 2];
                d = a.x - b.x; s2 += d * d;  d = a.y - b.y; s2 += d * d;
                d = a.z - b.z; s2 += d * d;  d = a.w - b.w; s2 += d * d;
                a = pa[k + 3]; b = pb[k + 3];
                d = a.x - b.x; s3 += d * d;  d = a.y - b.y; s3 += d * d;
                d = a.z - b.z; s3 += d * d;  d = a.w - b.w; s3 += d * d;
            }
            const float dd = sqrtf((s0 + s1) + (s2 + s3));
            if (dd > t0) { t1 = t0; t0 = dd; }
            else if (dd > t1) { t1 = dd; }
        }
    }

    // ONE butterfly top-2 merge per wave (not per pair)
#pragma unroll
    for (int off = 32; off > 0; off >>= 1) {
        const float o0 = __shfl_xor(t0, off, 64);
        const float o1 = __shfl_xor(t1, off, 64);
        if (o0 > t0) { t1 = fmaxf(t0, o1); t0 = o0; }
        else         { t1 = fmaxf(t1, o0); }
    }

    __shared__ float sm0[4], sm1[4];
    if (lane == 0) { sm0[wave] = t0; sm1[wave] = t1; }
    __syncthreads();
    if (t == 0) {
        float b0 = -INFINITY, b1 = -INFINITY;
        for (int w = 0; w < 4; ++w) {
            const float a0 = sm0[w], a1 = sm1[w];
            if (a0 > b0) { b1 = b0; b0 = a0; } else if (a0 > b1) { b1 = a0; }
            if (a1 > b0) { b1 = b0; b0 = a1; } else if (a1 > b1) { b1 = a1; }
        }
        const int s = blockIdx.y - 1;
        blk_top[(c * S2 + s) * 2]     = b0;
        blk_top[(c * S2 + s) * 2 + 1] = b1;
    }
}

// ---------------- K2: center-min + class merge + last-block finish ---------

__global__ void __launch_bounds__(256)
k2_kernel(const float* __restrict__ centers,
          const float* __restrict__ blk_top,
          float* __restrict__ cmin,
          float* __restrict__ li,
          int* __restrict__ cnt,
          float* __restrict__ out) {
    const int bid = blockIdx.x;
    const int t = threadIdx.x;
    const int wave = t >> 6;
    const int lane = t & 63;

    if (bid < 256) {
        // ---- center-min: one (i,j) slot per wave, lanes split D ----
        __shared__ float sm[4];
        const int slot = bid * 4 + wave;
        const int i = slot >> 5;
        const int j = slot & 31;
        float dd = INFINITY;
        if (i < j) {
            const float4* ca = (const float4*)(centers + i * D) + lane * 2;
            const float4* cb = (const float4*)(centers + j * D) + lane * 2;
            const float4 u0 = ca[0], u1 = ca[1];
            const float4 v0 = cb[0], v1 = cb[1];
            float d, ssd = 0.f;
            d = u0.x - v0.x; ssd += d * d;
            d = u0.y - v0.y; ssd += d * d;
            d = u0.z - v0.z; ssd += d * d;
            d = u0.w - v0.w; ssd += d * d;
            d = u1.x - v1.x; ssd += d * d;
            d = u1.y - v1.y; ssd += d * d;
            d = u1.z - v1.z; ssd += d * d;
            d = u1.w - v1.w; ssd += d * d;
#pragma unroll
            for (int off = 32; off > 0; off >>= 1)
                ssd += __shfl_xor(ssd, off, 64);
            dd = sqrtf(ssd);
        }
        if (lane == 0) sm[wave] = dd;
        __syncthreads();
        if (t == 0) {
            float m = INFINITY;
            for (int w = 0; w < 4; ++w) m = fminf(m, sm[w]);
            cmin[bid] = m;
        }
    } else if (wave == 0) {
        // ---- per-class top-2 merge: S2*2 = 18 partials on 18 lanes ----
        const int c = bid - 256;
        float t0 = (lane < S2 * 2) ? blk_top[c * S2 * 2 + lane] : -INFINITY;
        float t1 = -INFINITY;
#pragma unroll
        for (int off = 32; off > 0; off >>= 1) {
            const float o0 = __shfl_xor(t0, off, 64);
            const float o1 = __shfl_xor(t1, off, 64);
            if (o0 > t0) { t1 = fmaxf(t0, o1); t0 = o0; }
            else         { t1 = fmaxf(t1, o0); }
        }
        if (lane == 0) li[c] = 2.0f / (t0 + t1);
    }

    // ---- last-arriving block does the tiny final combine ----
    __shared__ int isLast;
    __threadfence();
    __syncthreads();
    if (t == 0) {
        const int old = atomicAdd(cnt, 1);
        isLast = (old == K2_BLOCKS - 1) ? 1 : 0;
    }
    __syncthreads();
    if (isLast) {
        __threadfence();
        __shared__ float mn_sh[4];
        float v = cmin[wave * 64 + lane];
#pragma unroll
        for (int off = 32; off > 0; off >>= 1)
            v = fminf(v, __shfl_xor(v, off, 64));
        if (lane == 0) mn_sh[wave] = v;
        __syncthreads();
        if (t == 0) {
            float m = INFINITY;
            for (int w = 0; w < 4; ++w) m = fminf(m, mn_sh[w]);
            float s = 0.f;
            for (int c = 0; c < NC; ++c) s += li[c];
            out[0] = 1.0f * s + 0.5f * fmaxf(10.0f - m, 0.0f);
        }
    }
}

extern "C" void kernel_launch(void* const* d_in, const int* in_sizes, int n_in,
                              void* d_out, int out_size, void* d_ws, size_t ws_size,
                              hipStream_t stream) {
    const float* y      = (const float*)d_in[0];
    const int*   target = (const int*)d_in[1];
    float*       out    = (float*)d_out;

    float* centers = (float*)d_ws;
    float* blk_top = centers + NC * D;
    float* cmin    = blk_top + NC * S2 * 2;
    float* li      = cmin + 256;
    int*   cnt     = (int*)(li + NC);

    k1_kernel<<<dim3(NC, S2 + 1), 256, 0, stream>>>(y, target, centers, blk_top, cnt);
    k2_kernel<<<K2_BLOCKS, 256, 0, stream>>>(centers, blk_top, cmin, li, cnt, out);
}

// Round 8
// 43.666 us; speedup vs baseline: 9.9845x; 1.7977x over previous
//
#include <hip/hip_runtime.h>
#include <math.h>

#define B 2048
#define D 512
#define NC 32
#define G  32                   // subtile-blocks per class (64 top2 partials = 1 wave)
#define TS 516                  // LDS tile row stride in floats (512 + 4 pad)
#define K2_BLOCKS (256 + NC)

// ---------------------------------------------------------------------------
// Workspace: float centers[NC][D]; float blk_top[NC][G][2];
//            float cmin[256]; float li[NC]; int cnt
// ---------------------------------------------------------------------------

// Build class-c member list (ascending order) in LDS via wave shuffle-scan.
__device__ inline int build_slist(const int* __restrict__ target, int c,
                                  short* slist, int* wtot) {
    const int t = threadIdx.x;
    const int wave = t >> 6;
    const int lane = t & 63;
    const int base = t * 8;
    int flags[8];
    int local = 0;
#pragma unroll
    for (int k = 0; k < 8; ++k) {
        flags[k] = (target[base + k] == c) ? 1 : 0;
        local += flags[k];
    }
    int incl = local;
#pragma unroll
    for (int off = 1; off < 64; off <<= 1) {
        const int v = __shfl_up(incl, off, 64);
        if (lane >= off) incl += v;
    }
    if (lane == 63) wtot[wave] = incl;
    __syncthreads();
    int wbase = 0;
    for (int w = 0; w < wave; ++w) wbase += wtot[w];
    const int n = wtot[0] + wtot[1] + wtot[2] + wtot[3];
    int pos = wbase + incl - local;
#pragma unroll
    for (int k = 0; k < 8; ++k) {
        if (flags[k]) slist[pos++] = (short)(base + k);
    }
    __syncthreads();
    return n;
}

// ---------------- K1: centers + top2 (LDS-staged 8x8 subtile per block) ----

__global__ void __launch_bounds__(256)
k1_kernel(const float* __restrict__ y,
          const int* __restrict__ target,
          float* __restrict__ centers,
          float* __restrict__ blk_top,
          int* __restrict__ cnt) {
    const int c = blockIdx.x;
    const int t = threadIdx.x;
    const int wave = t >> 6;
    const int lane = t & 63;

    if (blockIdx.y == 0 && c == 0 && t == 0) *cnt = 0;  // reset K2 finish ctr

    __shared__ short slist[B];
    __shared__ int wtot[4];
    const int n = build_slist(target, c, slist, wtot);

    if (blockIdx.y == 0) {
        // -------- centers: thread owns dims t, t+256; 8-way unrolled gather
        float acc0 = 0.f, acc1 = 0.f;
        int m = 0;
        for (; m + 8 <= n; m += 8) {
#pragma unroll
            for (int k = 0; k < 8; ++k) {
                const float* r = y + (size_t)slist[m + k] * D;
                acc0 += r[t];
                acc1 += r[t + 256];
            }
        }
        for (; m < n; ++m) {
            const float* r = y + (size_t)slist[m] * D;
            acc0 += r[t];
            acc1 += r[t + 256];
        }
        const float den = fmaxf((float)n, 1.0f);
        centers[c * D + t]       = acc0 / den;
        centers[c * D + t + 256] = acc1 / den;
        return;
    }

    // -------- top2: one 8x8 subtile per block, staged in LDS ---------------
    __shared__ float tile[16 * TS];       // rows 0-7: a-side, 8-15: b-side
    __shared__ float partials[4][64];
    const int nt = (n + 7) >> 3;          // 8-row tiles
    const int nst = nt * (nt + 1) / 2;    // subtiles with ta <= tb

    const int di = lane >> 3;
    const int dj = lane & 7;
    float t0 = -INFINITY, t1 = -INFINITY;  // wave-0 running top2 (others unused)

    for (int st = blockIdx.y - 1; st < nst; st += G) {
        // decode st -> (ta, tb), ta <= tb, row-major over the triangle
        int rem = st, ta = 0;
        while (rem >= nt - ta) { rem -= nt - ta; ++ta; }
        const int tb = ta + rem;

        // ---- stage 16 rows (a: ta*8+r, b: tb*8+r) into LDS, bulk round ----
        {
            const int r  = t >> 4;              // 0..15
            const int cg = (t & 15) * 32;       // 32-float column chunk
            const int gidx = (r < 8) ? (ta * 8 + r) : (tb * 8 + (r - 8));
            const int row  = (gidx < n) ? (int)slist[gidx] : 0;
            const float4* src = (const float4*)(y + (size_t)row * D + cg);
            float4* dst = (float4*)&tile[r * TS + cg];
#pragma unroll
            for (int q = 0; q < 8; ++q) dst[q] = src[q];
        }
        __syncthreads();

        // ---- each lane: pair (di, dj); this wave covers 128 dims ----------
        {
            const float* pa = &tile[di * TS]        + wave * 128;
            const float* pb = &tile[(8 + dj) * TS]  + wave * 128;
            float s0 = 0.f, s1 = 0.f, s2 = 0.f, s3 = 0.f;
#pragma unroll
            for (int kk = 0; kk < 32; kk += 4) {
                float4 a, b; float d;
                a = ((const float4*)pa)[kk];     b = ((const float4*)pb)[kk];
                d = a.x - b.x; s0 += d * d;  d = a.y - b.y; s0 += d * d;
                d = a.z - b.z; s0 += d * d;  d = a.w - b.w; s0 += d * d;
                a = ((const float4*)pa)[kk + 1]; b = ((const float4*)pb)[kk + 1];
                d = a.x - b.x; s1 += d * d;  d = a.y - b.y; s1 += d * d;
                d = a.z - b.z; s1 += d * d;  d = a.w - b.w; s1 += d * d;
                a = ((const float4*)pa)[kk + 2]; b = ((const float4*)pb)[kk + 2];
                d = a.x - b.x; s2 += d * d;  d = a.y - b.y; s2 += d * d;
                d = a.z - b.z; s2 += d * d;  d = a.w - b.w; s2 += d * d;
                a = ((const float4*)pa)[kk + 3]; b = ((const float4*)pb)[kk + 3];
                d = a.x - b.x; s3 += d * d;  d = a.y - b.y; s3 += d * d;
                d = a.z - b.z; s3 += d * d;  d = a.w - b.w; s3 += d * d;
            }
            partials[wave][lane] = (s0 + s1) + (s2 + s3);
        }
        __syncthreads();

        // ---- wave 0: assemble full ssd per pair, update running top-2 -----
        if (wave == 0) {
            const float ssd = partials[0][lane] + partials[1][lane] +
                              partials[2][lane] + partials[3][lane];
            const int i = ta * 8 + di;
            const int j = tb * 8 + dj;
            const float dd = (i < j && j < n) ? sqrtf(ssd) : -INFINITY;
            if (dd > t0) { t1 = t0; t0 = dd; }
            else if (dd > t1) { t1 = dd; }
        }
        __syncthreads();   // tile reuse safety for next subtile
    }

    if (wave == 0) {
        // one butterfly top-2 merge across wave 0's 64 lanes
#pragma unroll
        for (int off = 32; off > 0; off >>= 1) {
            const float o0 = __shfl_xor(t0, off, 64);
            const float o1 = __shfl_xor(t1, off, 64);
            if (o0 > t0) { t1 = fmaxf(t0, o1); t0 = o0; }
            else         { t1 = fmaxf(t1, o0); }
        }
        if (lane == 0) {
            const int s = blockIdx.y - 1;
            blk_top[(c * G + s) * 2]     = t0;
            blk_top[(c * G + s) * 2 + 1] = t1;
        }
    }
}

// ---------------- K2: center-min + class merge + last-block finish ---------

__global__ void __launch_bounds__(256)
k2_kernel(const float* __restrict__ centers,
          const float* __restrict__ blk_top,
          float* __restrict__ cmin,
          float* __restrict__ li,
          int* __restrict__ cnt,
          float* __restrict__ out) {
    const int bid = blockIdx.x;
    const int t = threadIdx.x;
    const int wave = t >> 6;
    const int lane = t & 63;

    if (bid < 256) {
        // ---- center-min: one (i,j) slot per wave, lanes split D ----
        __shared__ float sm[4];
        const int slot = bid * 4 + wave;
        const int i = slot >> 5;
        const int j = slot & 31;
        float dd = INFINITY;
        if (i < j) {
            const float4* ca = (const float4*)(centers + i * D) + lane * 2;
            const float4* cb = (const float4*)(centers + j * D) + lane * 2;
            const float4 u0 = ca[0], u1 = ca[1];
            const float4 v0 = cb[0], v1 = cb[1];
            float d, ssd = 0.f;
            d = u0.x - v0.x; ssd += d * d;
            d = u0.y - v0.y; ssd += d * d;
            d = u0.z - v0.z; ssd += d * d;
            d = u0.w - v0.w; ssd += d * d;
            d = u1.x - v1.x; ssd += d * d;
            d = u1.y - v1.y; ssd += d * d;
            d = u1.z - v1.z; ssd += d * d;
            d = u1.w - v1.w; ssd += d * d;
#pragma unroll
            for (int off = 32; off > 0; off >>= 1)
                ssd += __shfl_xor(ssd, off, 64);
            dd = sqrtf(ssd);
        }
        if (lane == 0) sm[wave] = dd;
        __syncthreads();
        if (t == 0) {
            float m = INFINITY;
            for (int w = 0; w < 4; ++w) m = fminf(m, sm[w]);
            cmin[bid] = m;
        }
    } else if (wave == 0) {
        // ---- per-class top-2 merge: G*2 = 64 partials on 64 lanes ----
        const int c = bid - 256;
        float t0 = blk_top[c * G * 2 + lane];
        float t1 = -INFINITY;
#pragma unroll
        for (int off = 32; off > 0; off >>= 1) {
            const float o0 = __shfl_xor(t0, off, 64);
            const float o1 = __shfl_xor(t1, off, 64);
            if (o0 > t0) { t1 = fmaxf(t0, o1); t0 = o0; }
            else         { t1 = fmaxf(t1, o0); }
        }
        if (lane == 0) li[c] = 2.0f / (t0 + t1);
    }

    // ---- last-arriving block does the tiny final combine ----
    __shared__ int isLast;
    __threadfence();
    __syncthreads();
    if (t == 0) {
        const int old = atomicAdd(cnt, 1);
        isLast = (old == K2_BLOCKS - 1) ? 1 : 0;
    }
    __syncthreads();
    if (isLast) {
        __threadfence();
        __shared__ float mn_sh[4];
        float v = cmin[wave * 64 + lane];
#pragma unroll
        for (int off = 32; off > 0; off >>= 1)
            v = fminf(v, __shfl_xor(v, off, 64));
        if (lane == 0) mn_sh[wave] = v;
        __syncthreads();
        if (t == 0) {
            float m = INFINITY;
            for (int w = 0; w < 4; ++w) m = fminf(m, mn_sh[w]);
            float s = 0.f;
            for (int c = 0; c < NC; ++c) s += li[c];
            out[0] = 1.0f * s + 0.5f * fmaxf(10.0f - m, 0.0f);
        }
    }
}

extern "C" void kernel_launch(void* const* d_in, const int* in_sizes, int n_in,
                              void* d_out, int out_size, void* d_ws, size_t ws_size,
                              hipStream_t stream) {
    const float* y      = (const float*)d_in[0];
    const int*   target = (const int*)d_in[1];
    float*       out    = (float*)d_out;

    float* centers = (float*)d_ws;
    float* blk_top = centers + NC * D;
    float* cmin    = blk_top + NC * G * 2;
    float* li      = cmin + 256;
    int*   cnt     = (int*)(li + NC);

    k1_kernel<<<dim3(NC, G + 1), 256, 0, stream>>>(y, target, centers, blk_top, cnt);
    k2_kernel<<<K2_BLOCKS, 256, 0, stream>>>(centers, blk_top, cmin, li, cnt, out);
}